// Round 1
// baseline (1541.273 us; speedup 1.0000x reference)
//
#include <hip/hip_runtime.h>
#include <math.h>

#define BB 4
#define TT 8192
#define EE 8
#define HH 1024
#define HPD 128
#define KSEL 1024
#define QW 384   // 3*HP

// ---- workspace layout (bytes) ----
#define OFF_L    ((size_t)0)                                   // float[B*T*E]      1 MB
#define OFF_IDX  (OFF_L   + (size_t)BB*TT*EE*4)                // int[B*E*K]        128 KB
#define OFF_GATE (OFF_IDX + (size_t)BB*EE*KSEL*4)              // float[B*E*K]      128 KB
#define OFF_QKV  (OFF_GATE+ (size_t)BB*EE*KSEL*4)              // float[B*E*K*384]  48 MB
#define OFF_AV   (OFF_QKV + (size_t)BB*EE*KSEL*QW*4)           // float[B*E*K*128]  16 MB

// ---------------- 1. router: L[b,t,e] = X[b,t,:] . Wr[e,:]  (fp64 accum) ----------------
__global__ __launch_bounds__(256) void router_kernel(const float* __restrict__ X,
                                                     const float* __restrict__ Wr,
                                                     float* __restrict__ L) {
    __shared__ float wr_s[EE * HH];
    int tid = threadIdx.x;
    for (int i = tid; i < EE * HH; i += 256) wr_s[i] = Wr[i];
    __syncthreads();
    int wave = tid >> 6, lane = tid & 63;
    int row = blockIdx.x * 4 + wave;              // row in [0, B*T)
    const float* xr = X + (size_t)row * HH;
    double acc[EE];
#pragma unroll
    for (int e = 0; e < EE; e++) acc[e] = 0.0;
#pragma unroll
    for (int it = 0; it < 4; it++) {
        int d0 = it * 256 + lane * 4;
        float4 x4 = *(const float4*)(xr + d0);
#pragma unroll
        for (int e = 0; e < EE; e++) {
            float4 w4 = *(const float4*)(wr_s + e * HH + d0);
            acc[e] += (double)x4.x * w4.x + (double)x4.y * w4.y +
                      (double)x4.z * w4.z + (double)x4.w * w4.w;
        }
    }
#pragma unroll
    for (int off = 32; off > 0; off >>= 1)
#pragma unroll
        for (int e = 0; e < EE; e++) acc[e] += __shfl_xor(acc[e], off, 64);
    if (lane < EE) L[(size_t)row * EE + lane] = (float)acc[lane];
}

// ---------------- 2. top-k via full bitonic sort (desc value, asc index ties) ----------------
__global__ __launch_bounds__(1024) void topk_kernel(const float* __restrict__ L,
                                                    int* __restrict__ topk_idx,
                                                    float* __restrict__ gate) {
    __shared__ unsigned long long s[TT];          // 64 KB
    int be = blockIdx.x, b = be >> 3, e = be & 7;
    for (int t = threadIdx.x; t < TT; t += 1024) {
        float v = L[((size_t)b * TT + t) * EE + e];
        unsigned u = __float_as_uint(v);
        u ^= (u >> 31) ? 0xFFFFFFFFu : 0x80000000u;   // sortable: asc uint == asc float
        unsigned inv = ~u;                            // asc inv == desc float
        s[t] = ((unsigned long long)inv << 32) | (unsigned)t;
    }
    __syncthreads();
    for (int size = 2; size <= TT; size <<= 1) {
        for (int stride = size >> 1; stride > 0; stride >>= 1) {
            for (int t = threadIdx.x; t < TT / 2; t += 1024) {
                int j = t & (stride - 1);
                int lo = ((t ^ j) << 1) | j;
                int hi = lo + stride;
                unsigned long long a = s[lo], c = s[hi];
                bool asc = ((lo & size) == 0);
                if ((a > c) == asc) { s[lo] = c; s[hi] = a; }
            }
            __syncthreads();
        }
    }
    for (int i = threadIdx.x; i < KSEL; i += 1024) {
        int idx = (int)(unsigned)s[i];
        float v = L[((size_t)b * TT + idx) * EE + e];
        topk_idx[be * KSEL + i] = idx;
        gate[be * KSEL + i] = 1.0f / (1.0f + expf(-v));
    }
}

// ---------------- 3. QKV GEMM: gathered X rows (1024x1024) @ Wqkv[e] (1024x384) ----------------
// block: M=64 rows x N=128 cols, K-step 16.  threads 16x16, each 4 rows x 8 cols.
__global__ __launch_bounds__(256) void qkv_kernel(const float* __restrict__ X,
                                                  const float* __restrict__ Wqkv,
                                                  const int* __restrict__ topk_idx,
                                                  float* __restrict__ QKV) {
    __shared__ float As[16][68];    // [kk][m]
    __shared__ float Bs[16][132];   // [kk][n]
    __shared__ int rows_s[64];
    int mt = blockIdx.x, nt = blockIdx.y, be = blockIdx.z;
    int b = be >> 3, e = be & 7;
    int tid = threadIdx.x, tx = tid & 15, ty = tid >> 4;
    if (tid < 64) rows_s[tid] = topk_idx[be * KSEL + mt * 64 + tid];
    __syncthreads();
    int n0 = nt * 128;
    float acc[4][2][4];
#pragma unroll
    for (int r = 0; r < 4; r++)
#pragma unroll
        for (int g = 0; g < 2; g++)
#pragma unroll
            for (int c = 0; c < 4; c++) acc[r][g][c] = 0.f;
    const float* xb = X + (size_t)b * TT * HH;
    const float* wb = Wqkv + (size_t)e * HH * QW;
    int am = tid >> 2, akg = tid & 3;
    size_t arow = (size_t)rows_s[am] * HH;
    int bkk = tid >> 4, bng = tid & 15;
    for (int k0 = 0; k0 < HH; k0 += 16) {
        float4 a4 = *(const float4*)(xb + arow + k0 + akg * 4);
        float4 b0 = *(const float4*)(wb + (size_t)(k0 + bkk) * QW + n0 + bng * 4);
        float4 b1 = *(const float4*)(wb + (size_t)(k0 + bkk) * QW + n0 + 64 + bng * 4);
        As[akg * 4 + 0][am] = a4.x; As[akg * 4 + 1][am] = a4.y;
        As[akg * 4 + 2][am] = a4.z; As[akg * 4 + 3][am] = a4.w;
        *(float4*)&Bs[bkk][bng * 4] = b0;
        *(float4*)&Bs[bkk][64 + bng * 4] = b1;
        __syncthreads();
#pragma unroll
        for (int kk = 0; kk < 16; kk++) {
            float ar[4];
#pragma unroll
            for (int r = 0; r < 4; r++) ar[r] = As[kk][16 * r + ty];
            float4 v0 = *(float4*)&Bs[kk][tx * 4];
            float4 v1 = *(float4*)&Bs[kk][64 + tx * 4];
#pragma unroll
            for (int r = 0; r < 4; r++) {
                acc[r][0][0] += ar[r] * v0.x; acc[r][0][1] += ar[r] * v0.y;
                acc[r][0][2] += ar[r] * v0.z; acc[r][0][3] += ar[r] * v0.w;
                acc[r][1][0] += ar[r] * v1.x; acc[r][1][1] += ar[r] * v1.y;
                acc[r][1][2] += ar[r] * v1.z; acc[r][1][3] += ar[r] * v1.w;
            }
        }
        __syncthreads();
    }
#pragma unroll
    for (int r = 0; r < 4; r++)
#pragma unroll
        for (int g = 0; g < 2; g++)
            *(float4*)(QKV + ((size_t)be * KSEL + mt * 64 + 16 * r + ty) * QW + n0 + g * 64 + tx * 4) =
                *(float4*)&acc[r][g][0];
}

// ---------------- 4. RoPE on Q[:,:64] and K[:,:64], pos = selected token index ----------------
__global__ __launch_bounds__(256) void rope_kernel(float* __restrict__ QKV,
                                                   const int* __restrict__ topk_idx) {
    int tid = threadIdx.x;
    int r = blockIdx.x * 4 + (tid >> 6);          // row in [0, B*E*K)
    int lane = tid & 63;
    int j = lane & 31;
    int pos = topk_idx[r];
    float* base = QKV + (size_t)r * QW + ((lane < 32) ? 0 : HPD);
    double inv = pow(10000.0, -(double)(2 * j) / 64.0);
    double ang = (double)pos * inv;
    float sn = (float)sin(ang), cs = (float)cos(ang);
    float x1 = base[j], x2 = base[j + 32];
    base[j] = x1 * cs - x2 * sn;
    base[j + 32] = x2 * cs + x1 * sn;
}

// ---------------- 5. flash attention per (b,e): Tq=32, Tk=64, online softmax, gate fused ----------------
__global__ __launch_bounds__(256) void attn_kernel(const float* __restrict__ QKV,
                                                   const int* __restrict__ topk_idx,
                                                   const float* __restrict__ gate,
                                                   float* __restrict__ AV) {
    __shared__ float Qs[32][132];
    __shared__ float KVs[64][132];
    __shared__ float Ps[32][68];
    __shared__ int pos_q[32];
    __shared__ int pos_k[64];
    int qt = blockIdx.x, be = blockIdx.y;
    int tid = threadIdx.x, tx = tid & 15, ty = tid >> 4;
    int q0 = qt * 32;
    const float* qkv_be = QKV + (size_t)be * KSEL * QW;
    const int* idx_be = topk_idx + be * KSEL;
    const float scale = 0.08838834764831845f;     // 1/sqrt(128)
    for (int i = tid; i < 32 * 32; i += 256) {    // 32 rows x 32 float4
        int row = i >> 5, seg = i & 31;
        float4 v = *(const float4*)(qkv_be + (size_t)(q0 + row) * QW + seg * 4);
        v.x *= scale; v.y *= scale; v.z *= scale; v.w *= scale;
        *(float4*)&Qs[row][seg * 4] = v;
    }
    if (tid < 32) pos_q[tid] = idx_be[q0 + tid];
    float m[2] = {-INFINITY, -INFINITY}, l[2] = {0.f, 0.f};
    float O[2][2][4];
#pragma unroll
    for (int r = 0; r < 2; r++)
#pragma unroll
        for (int g = 0; g < 2; g++)
#pragma unroll
            for (int c = 0; c < 4; c++) O[r][g][c] = 0.f;
    __syncthreads();
    int pq[2] = {pos_q[ty], pos_q[16 + ty]};
    for (int kt = 0; kt < 16; kt++) {
        int k0 = kt * 64;
        __syncthreads();                           // KVs free (prev PV done)
        for (int i = tid; i < 64 * 32; i += 256) { // K tile
            int row = i >> 5, seg = i & 31;
            *(float4*)&KVs[row][seg * 4] =
                *(const float4*)(qkv_be + (size_t)(k0 + row) * QW + HPD + seg * 4);
        }
        if (tid < 64) pos_k[tid] = idx_be[k0 + tid];
        __syncthreads();
        float s[2][4];
#pragma unroll
        for (int r = 0; r < 2; r++)
#pragma unroll
            for (int c = 0; c < 4; c++) s[r][c] = 0.f;
        for (int dd = 0; dd < 128; dd += 4) {
            float4 qa = *(float4*)&Qs[ty][dd];
            float4 qb = *(float4*)&Qs[16 + ty][dd];
            float4 kv[4];
#pragma unroll
            for (int c = 0; c < 4; c++) kv[c] = *(float4*)&KVs[16 * c + tx][dd];
#pragma unroll
            for (int c = 0; c < 4; c++) {
                s[0][c] += qa.x * kv[c].x + qa.y * kv[c].y + qa.z * kv[c].z + qa.w * kv[c].w;
                s[1][c] += qb.x * kv[c].x + qb.y * kv[c].y + qb.z * kv[c].z + qb.w * kv[c].w;
            }
        }
        int pk[4];
#pragma unroll
        for (int c = 0; c < 4; c++) pk[c] = pos_k[16 * c + tx];
        float alpha[2];
#pragma unroll
        for (int r = 0; r < 2; r++) {
            float mr = -INFINITY;
            bool msk[4];
#pragma unroll
            for (int c = 0; c < 4; c++) {
                msk[c] = (pq[r] >= pk[c]);
                if (!msk[c]) s[r][c] = -INFINITY;
                mr = fmaxf(mr, s[r][c]);
            }
#pragma unroll
            for (int off = 1; off < 16; off <<= 1) mr = fmaxf(mr, __shfl_xor(mr, off, 64));
            float mnew = fmaxf(m[r], mr);
            alpha[r] = (mnew == -INFINITY) ? 1.f : expf(m[r] - mnew);
            float rs = 0.f;
#pragma unroll
            for (int c = 0; c < 4; c++) {
                float p = msk[c] ? expf(s[r][c] - mnew) : 0.f;
                s[r][c] = p; rs += p;
            }
#pragma unroll
            for (int off = 1; off < 16; off <<= 1) rs += __shfl_xor(rs, off, 64);
            l[r] = l[r] * alpha[r] + rs;
            m[r] = mnew;
#pragma unroll
            for (int c = 0; c < 4; c++) Ps[16 * r + ty][16 * c + tx] = s[r][c];
        }
        __syncthreads();                           // Ps written; KVs free for V
        for (int i = tid; i < 64 * 32; i += 256) { // V tile
            int row = i >> 5, seg = i & 31;
            *(float4*)&KVs[row][seg * 4] =
                *(const float4*)(qkv_be + (size_t)(k0 + row) * QW + 2 * HPD + seg * 4);
        }
        __syncthreads();
#pragma unroll
        for (int r = 0; r < 2; r++)
#pragma unroll
            for (int g = 0; g < 2; g++)
#pragma unroll
                for (int c = 0; c < 4; c++) O[r][g][c] *= alpha[r];
        for (int jj = 0; jj < 64; jj++) {
            float p0 = Ps[ty][jj], p1 = Ps[16 + ty][jj];
            float4 v0 = *(float4*)&KVs[jj][tx * 4];
            float4 v1 = *(float4*)&KVs[jj][64 + tx * 4];
            O[0][0][0] += p0 * v0.x; O[0][0][1] += p0 * v0.y; O[0][0][2] += p0 * v0.z; O[0][0][3] += p0 * v0.w;
            O[0][1][0] += p0 * v1.x; O[0][1][1] += p0 * v1.y; O[0][1][2] += p0 * v1.z; O[0][1][3] += p0 * v1.w;
            O[1][0][0] += p1 * v0.x; O[1][0][1] += p1 * v0.y; O[1][0][2] += p1 * v0.z; O[1][0][3] += p1 * v0.w;
            O[1][1][0] += p1 * v1.x; O[1][1][1] += p1 * v1.y; O[1][1][2] += p1 * v1.z; O[1][1][3] += p1 * v1.w;
        }
    }
#pragma unroll
    for (int r = 0; r < 2; r++) {
        int grow = q0 + 16 * r + ty;
        float gsc = gate[be * KSEL + grow] / l[r];
        float4 o0, o1;
        o0.x = O[r][0][0] * gsc; o0.y = O[r][0][1] * gsc; o0.z = O[r][0][2] * gsc; o0.w = O[r][0][3] * gsc;
        o1.x = O[r][1][0] * gsc; o1.y = O[r][1][1] * gsc; o1.z = O[r][1][2] * gsc; o1.w = O[r][1][3] * gsc;
        *(float4*)(AV + ((size_t)be * KSEL + grow) * HPD + tx * 4) = o0;
        *(float4*)(AV + ((size_t)be * KSEL + grow) * HPD + 64 + tx * 4) = o1;
    }
}

// ---------------- 6. out projection AV(64x128) @ Wo[e](128x1024 tile 128) + atomic scatter ----------------
__global__ __launch_bounds__(256) void proj_kernel(const float* __restrict__ AV,
                                                   const float* __restrict__ Wo,
                                                   const int* __restrict__ topk_idx,
                                                   float* __restrict__ out) {
    __shared__ float As[16][68];
    __shared__ float Bs[16][132];
    __shared__ int rows_s[64];
    int mt = blockIdx.x, nt = blockIdx.y, be = blockIdx.z;
    int b = be >> 3, e = be & 7;
    int tid = threadIdx.x, tx = tid & 15, ty = tid >> 4;
    if (tid < 64) rows_s[tid] = topk_idx[be * KSEL + mt * 64 + tid];
    __syncthreads();
    int n0 = nt * 128;
    float acc[4][2][4];
#pragma unroll
    for (int r = 0; r < 4; r++)
#pragma unroll
        for (int g = 0; g < 2; g++)
#pragma unroll
            for (int c = 0; c < 4; c++) acc[r][g][c] = 0.f;
    const float* ab = AV + ((size_t)be * KSEL + mt * 64) * HPD;
    const float* wb = Wo + (size_t)e * HPD * HH;
    int am = tid >> 2, akg = tid & 3;
    int bkk = tid >> 4, bng = tid & 15;
    for (int k0 = 0; k0 < HPD; k0 += 16) {
        float4 a4 = *(const float4*)(ab + (size_t)am * HPD + k0 + akg * 4);
        float4 b0 = *(const float4*)(wb + (size_t)(k0 + bkk) * HH + n0 + bng * 4);
        float4 b1 = *(const float4*)(wb + (size_t)(k0 + bkk) * HH + n0 + 64 + bng * 4);
        As[akg * 4 + 0][am] = a4.x; As[akg * 4 + 1][am] = a4.y;
        As[akg * 4 + 2][am] = a4.z; As[akg * 4 + 3][am] = a4.w;
        *(float4*)&Bs[bkk][bng * 4] = b0;
        *(float4*)&Bs[bkk][64 + bng * 4] = b1;
        __syncthreads();
#pragma unroll
        for (int kk = 0; kk < 16; kk++) {
            float ar[4];
#pragma unroll
            for (int r = 0; r < 4; r++) ar[r] = As[kk][16 * r + ty];
            float4 v0 = *(float4*)&Bs[kk][tx * 4];
            float4 v1 = *(float4*)&Bs[kk][64 + tx * 4];
#pragma unroll
            for (int r = 0; r < 4; r++) {
                acc[r][0][0] += ar[r] * v0.x; acc[r][0][1] += ar[r] * v0.y;
                acc[r][0][2] += ar[r] * v0.z; acc[r][0][3] += ar[r] * v0.w;
                acc[r][1][0] += ar[r] * v1.x; acc[r][1][1] += ar[r] * v1.y;
                acc[r][1][2] += ar[r] * v1.z; acc[r][1][3] += ar[r] * v1.w;
            }
        }
        __syncthreads();
    }
#pragma unroll
    for (int r = 0; r < 4; r++) {
        int pos = rows_s[16 * r + ty];
        float* ob = out + ((size_t)b * TT + pos) * HH + n0;
#pragma unroll
        for (int g = 0; g < 2; g++)
#pragma unroll
            for (int c = 0; c < 4; c++)
                atomicAdd(ob + g * 64 + tx * 4 + c, acc[r][g][c]);
    }
}

extern "C" void kernel_launch(void* const* d_in, const int* in_sizes, int n_in,
                              void* d_out, int out_size, void* d_ws, size_t ws_size,
                              hipStream_t stream) {
    const float* X    = (const float*)d_in[0];
    const float* Wr   = (const float*)d_in[1];
    const float* Wqkv = (const float*)d_in[2];
    const float* Wo   = (const float*)d_in[3];
    float* out = (float*)d_out;
    char* ws = (char*)d_ws;
    float* L    = (float*)(ws + OFF_L);
    int*   idx  = (int*)(ws + OFF_IDX);
    float* gate = (float*)(ws + OFF_GATE);
    float* QKV  = (float*)(ws + OFF_QKV);
    float* AV   = (float*)(ws + OFF_AV);

    hipMemsetAsync(d_out, 0, (size_t)BB * TT * HH * sizeof(float), stream);
    router_kernel<<<BB * TT / 4, 256, 0, stream>>>(X, Wr, L);
    topk_kernel<<<BB * EE, 1024, 0, stream>>>(L, idx, gate);
    qkv_kernel<<<dim3(KSEL / 64, 3, BB * EE), 256, 0, stream>>>(X, Wqkv, idx, QKV);
    rope_kernel<<<BB * EE * KSEL / 4, 256, 0, stream>>>(QKV, idx);
    attn_kernel<<<dim3(KSEL / 32, BB * EE), 256, 0, stream>>>(QKV, idx, gate, AV);
    proj_kernel<<<dim3(KSEL / 64, HH / 128, BB * EE), 256, 0, stream>>>(AV, Wo, idx, out);
}

// Round 2
// 1209.313 us; speedup vs baseline: 1.2745x; 1.2745x over previous
//
#include <hip/hip_runtime.h>
#include <math.h>

#define BB 4
#define TT 8192
#define EE 8
#define HH 1024
#define HPD 128
#define KSEL 1024
#define QW 384   // 3*HP

// ---- workspace layout (bytes) ----
#define OFF_L    ((size_t)0)                                   // float[B*T*E]      1 MB
#define OFF_IDX  (OFF_L   + (size_t)BB*TT*EE*4)                // int[B*E*K]        128 KB
#define OFF_GATE (OFF_IDX + (size_t)BB*EE*KSEL*4)              // float[B*E*K]      128 KB
#define OFF_QKV  (OFF_GATE+ (size_t)BB*EE*KSEL*4)              // float[B*E*K*384]  48 MB
#define OFF_AV   (OFF_QKV + (size_t)BB*EE*KSEL*QW*4)           // float[B*E*K*128]  16 MB

// ---------------- 1. router: L[b,t,e] = X[b,t,:] . Wr[e,:]  (fp64 accum) ----------------
__global__ __launch_bounds__(256) void router_kernel(const float* __restrict__ X,
                                                     const float* __restrict__ Wr,
                                                     float* __restrict__ L) {
    __shared__ float wr_s[EE * HH];
    int tid = threadIdx.x;
    for (int i = tid; i < EE * HH; i += 256) wr_s[i] = Wr[i];
    __syncthreads();
    int wave = tid >> 6, lane = tid & 63;
    int row = blockIdx.x * 4 + wave;              // row in [0, B*T)
    const float* xr = X + (size_t)row * HH;
    double acc[EE];
#pragma unroll
    for (int e = 0; e < EE; e++) acc[e] = 0.0;
#pragma unroll
    for (int it = 0; it < 4; it++) {
        int d0 = it * 256 + lane * 4;
        float4 x4 = *(const float4*)(xr + d0);
#pragma unroll
        for (int e = 0; e < EE; e++) {
            float4 w4 = *(const float4*)(wr_s + e * HH + d0);
            acc[e] += (double)x4.x * w4.x + (double)x4.y * w4.y +
                      (double)x4.z * w4.z + (double)x4.w * w4.w;
        }
    }
#pragma unroll
    for (int off = 32; off > 0; off >>= 1)
#pragma unroll
        for (int e = 0; e < EE; e++) acc[e] += __shfl_xor(acc[e], off, 64);
    if (lane < EE) L[(size_t)row * EE + lane] = (float)acc[lane];
}

// ---------------- 2. top-k via full bitonic sort (desc value, asc index ties) ----------------
__global__ __launch_bounds__(1024) void topk_kernel(const float* __restrict__ L,
                                                    int* __restrict__ topk_idx,
                                                    float* __restrict__ gate) {
    __shared__ unsigned long long s[TT];          // 64 KB
    int be = blockIdx.x, b = be >> 3, e = be & 7;
    for (int t = threadIdx.x; t < TT; t += 1024) {
        float v = L[((size_t)b * TT + t) * EE + e];
        unsigned u = __float_as_uint(v);
        u ^= (u >> 31) ? 0xFFFFFFFFu : 0x80000000u;   // sortable: asc uint == asc float
        unsigned inv = ~u;                            // asc inv == desc float
        s[t] = ((unsigned long long)inv << 32) | (unsigned)t;
    }
    __syncthreads();
    for (int size = 2; size <= TT; size <<= 1) {
        for (int stride = size >> 1; stride > 0; stride >>= 1) {
            for (int t = threadIdx.x; t < TT / 2; t += 1024) {
                int j = t & (stride - 1);
                int lo = ((t ^ j) << 1) | j;
                int hi = lo + stride;
                unsigned long long a = s[lo], c = s[hi];
                bool asc = ((lo & size) == 0);
                if ((a > c) == asc) { s[lo] = c; s[hi] = a; }
            }
            __syncthreads();
        }
    }
    for (int i = threadIdx.x; i < KSEL; i += 1024) {
        int idx = (int)(unsigned)s[i];
        float v = L[((size_t)b * TT + idx) * EE + e];
        topk_idx[be * KSEL + i] = idx;
        gate[be * KSEL + i] = 1.0f / (1.0f + expf(-v));
    }
}

// ---------------- 3. QKV GEMM: gathered X rows (1024x1024) @ Wqkv[e] (1024x384) ----------------
// block: M=64 rows x N=128 cols, K-step 16.  threads 16x16, each 4 rows x 8 cols.
__global__ __launch_bounds__(256) void qkv_kernel(const float* __restrict__ X,
                                                  const float* __restrict__ Wqkv,
                                                  const int* __restrict__ topk_idx,
                                                  float* __restrict__ QKV) {
    __shared__ float As[16][68];    // [kk][m]
    __shared__ float Bs[16][132];   // [kk][n]
    __shared__ int rows_s[64];
    int mt = blockIdx.x, nt = blockIdx.y, be = blockIdx.z;
    int b = be >> 3, e = be & 7;
    int tid = threadIdx.x, tx = tid & 15, ty = tid >> 4;
    if (tid < 64) rows_s[tid] = topk_idx[be * KSEL + mt * 64 + tid];
    __syncthreads();
    int n0 = nt * 128;
    float acc[4][2][4];
#pragma unroll
    for (int r = 0; r < 4; r++)
#pragma unroll
        for (int g = 0; g < 2; g++)
#pragma unroll
            for (int c = 0; c < 4; c++) acc[r][g][c] = 0.f;
    const float* xb = X + (size_t)b * TT * HH;
    const float* wb = Wqkv + (size_t)e * HH * QW;
    int am = tid >> 2, akg = tid & 3;
    size_t arow = (size_t)rows_s[am] * HH;
    int bkk = tid >> 4, bng = tid & 15;
    for (int k0 = 0; k0 < HH; k0 += 16) {
        float4 a4 = *(const float4*)(xb + arow + k0 + akg * 4);
        float4 b0 = *(const float4*)(wb + (size_t)(k0 + bkk) * QW + n0 + bng * 4);
        float4 b1 = *(const float4*)(wb + (size_t)(k0 + bkk) * QW + n0 + 64 + bng * 4);
        As[akg * 4 + 0][am] = a4.x; As[akg * 4 + 1][am] = a4.y;
        As[akg * 4 + 2][am] = a4.z; As[akg * 4 + 3][am] = a4.w;
        *(float4*)&Bs[bkk][bng * 4] = b0;
        *(float4*)&Bs[bkk][64 + bng * 4] = b1;
        __syncthreads();
#pragma unroll
        for (int kk = 0; kk < 16; kk++) {
            float ar[4];
#pragma unroll
            for (int r = 0; r < 4; r++) ar[r] = As[kk][16 * r + ty];
            float4 v0 = *(float4*)&Bs[kk][tx * 4];
            float4 v1 = *(float4*)&Bs[kk][64 + tx * 4];
#pragma unroll
            for (int r = 0; r < 4; r++) {
                acc[r][0][0] += ar[r] * v0.x; acc[r][0][1] += ar[r] * v0.y;
                acc[r][0][2] += ar[r] * v0.z; acc[r][0][3] += ar[r] * v0.w;
                acc[r][1][0] += ar[r] * v1.x; acc[r][1][1] += ar[r] * v1.y;
                acc[r][1][2] += ar[r] * v1.z; acc[r][1][3] += ar[r] * v1.w;
            }
        }
        __syncthreads();
    }
#pragma unroll
    for (int r = 0; r < 4; r++)
#pragma unroll
        for (int g = 0; g < 2; g++)
            *(float4*)(QKV + ((size_t)be * KSEL + mt * 64 + 16 * r + ty) * QW + n0 + g * 64 + tx * 4) =
                *(float4*)&acc[r][g][0];
}

// ---------------- 4. RoPE on Q[:,:64] and K[:,:64], pos = selected token index ----------------
__global__ __launch_bounds__(256) void rope_kernel(float* __restrict__ QKV,
                                                   const int* __restrict__ topk_idx) {
    int tid = threadIdx.x;
    int r = blockIdx.x * 4 + (tid >> 6);          // row in [0, B*E*K)
    int lane = tid & 63;
    int j = lane & 31;
    int pos = topk_idx[r];
    float* base = QKV + (size_t)r * QW + ((lane < 32) ? 0 : HPD);
    double inv = pow(10000.0, -(double)(2 * j) / 64.0);
    double ang = (double)pos * inv;
    float sn = (float)sin(ang), cs = (float)cos(ang);
    float x1 = base[j], x2 = base[j + 32];
    base[j] = x1 * cs - x2 * sn;
    base[j + 32] = x2 * cs + x1 * sn;
}

// ---------------- 5. flash attention per (b,e): Tq=32, Tk=64, online softmax, gate fused ----------------
__global__ __launch_bounds__(256) void attn_kernel(const float* __restrict__ QKV,
                                                   const int* __restrict__ topk_idx,
                                                   const float* __restrict__ gate,
                                                   float* __restrict__ AV) {
    __shared__ float Qs[32][132];
    __shared__ float KVs[64][132];
    __shared__ float Ps[32][68];
    __shared__ int pos_q[32];
    __shared__ int pos_k[64];
    int qt = blockIdx.x, be = blockIdx.y;
    int tid = threadIdx.x, tx = tid & 15, ty = tid >> 4;
    int q0 = qt * 32;
    const float* qkv_be = QKV + (size_t)be * KSEL * QW;
    const int* idx_be = topk_idx + be * KSEL;
    const float scale = 0.08838834764831845f;     // 1/sqrt(128)
    for (int i = tid; i < 32 * 32; i += 256) {    // 32 rows x 32 float4
        int row = i >> 5, seg = i & 31;
        float4 v = *(const float4*)(qkv_be + (size_t)(q0 + row) * QW + seg * 4);
        v.x *= scale; v.y *= scale; v.z *= scale; v.w *= scale;
        *(float4*)&Qs[row][seg * 4] = v;
    }
    if (tid < 32) pos_q[tid] = idx_be[q0 + tid];
    float m[2] = {-INFINITY, -INFINITY}, l[2] = {0.f, 0.f};
    float O[2][2][4];
#pragma unroll
    for (int r = 0; r < 2; r++)
#pragma unroll
        for (int g = 0; g < 2; g++)
#pragma unroll
            for (int c = 0; c < 4; c++) O[r][g][c] = 0.f;
    __syncthreads();
    int pq[2] = {pos_q[ty], pos_q[16 + ty]};
    for (int kt = 0; kt < 16; kt++) {
        int k0 = kt * 64;
        __syncthreads();                           // KVs free (prev PV done)
        for (int i = tid; i < 64 * 32; i += 256) { // K tile
            int row = i >> 5, seg = i & 31;
            *(float4*)&KVs[row][seg * 4] =
                *(const float4*)(qkv_be + (size_t)(k0 + row) * QW + HPD + seg * 4);
        }
        if (tid < 64) pos_k[tid] = idx_be[k0 + tid];
        __syncthreads();
        float s[2][4];
#pragma unroll
        for (int r = 0; r < 2; r++)
#pragma unroll
            for (int c = 0; c < 4; c++) s[r][c] = 0.f;
        for (int dd = 0; dd < 128; dd += 4) {
            float4 qa = *(float4*)&Qs[ty][dd];
            float4 qb = *(float4*)&Qs[16 + ty][dd];
            float4 kv[4];
#pragma unroll
            for (int c = 0; c < 4; c++) kv[c] = *(float4*)&KVs[16 * c + tx][dd];
#pragma unroll
            for (int c = 0; c < 4; c++) {
                s[0][c] += qa.x * kv[c].x + qa.y * kv[c].y + qa.z * kv[c].z + qa.w * kv[c].w;
                s[1][c] += qb.x * kv[c].x + qb.y * kv[c].y + qb.z * kv[c].z + qb.w * kv[c].w;
            }
        }
        int pk[4];
#pragma unroll
        for (int c = 0; c < 4; c++) pk[c] = pos_k[16 * c + tx];
        float alpha[2];
#pragma unroll
        for (int r = 0; r < 2; r++) {
            float mr = -INFINITY;
            bool msk[4];
#pragma unroll
            for (int c = 0; c < 4; c++) {
                msk[c] = (pq[r] >= pk[c]);
                if (!msk[c]) s[r][c] = -INFINITY;
                mr = fmaxf(mr, s[r][c]);
            }
#pragma unroll
            for (int off = 1; off < 16; off <<= 1) mr = fmaxf(mr, __shfl_xor(mr, off, 64));
            float mnew = fmaxf(m[r], mr);
            alpha[r] = (mnew == -INFINITY) ? 1.f : expf(m[r] - mnew);
            float rs = 0.f;
#pragma unroll
            for (int c = 0; c < 4; c++) {
                float p = msk[c] ? expf(s[r][c] - mnew) : 0.f;
                s[r][c] = p; rs += p;
            }
#pragma unroll
            for (int off = 1; off < 16; off <<= 1) rs += __shfl_xor(rs, off, 64);
            l[r] = l[r] * alpha[r] + rs;
            m[r] = mnew;
#pragma unroll
            for (int c = 0; c < 4; c++) Ps[16 * r + ty][16 * c + tx] = s[r][c];
        }
        __syncthreads();                           // Ps written; KVs free for V
        for (int i = tid; i < 64 * 32; i += 256) { // V tile
            int row = i >> 5, seg = i & 31;
            *(float4*)&KVs[row][seg * 4] =
                *(const float4*)(qkv_be + (size_t)(k0 + row) * QW + 2 * HPD + seg * 4);
        }
        __syncthreads();
#pragma unroll
        for (int r = 0; r < 2; r++)
#pragma unroll
            for (int g = 0; g < 2; g++)
#pragma unroll
                for (int c = 0; c < 4; c++) O[r][g][c] *= alpha[r];
        for (int jj = 0; jj < 64; jj++) {
            float p0 = Ps[ty][jj], p1 = Ps[16 + ty][jj];
            float4 v0 = *(float4*)&KVs[jj][tx * 4];
            float4 v1 = *(float4*)&KVs[jj][64 + tx * 4];
            O[0][0][0] += p0 * v0.x; O[0][0][1] += p0 * v0.y; O[0][0][2] += p0 * v0.z; O[0][0][3] += p0 * v0.w;
            O[0][1][0] += p0 * v1.x; O[0][1][1] += p0 * v1.y; O[0][1][2] += p0 * v1.z; O[0][1][3] += p0 * v1.w;
            O[1][0][0] += p1 * v0.x; O[1][0][1] += p1 * v0.y; O[1][0][2] += p1 * v0.z; O[1][0][3] += p1 * v0.w;
            O[1][1][0] += p1 * v1.x; O[1][1][1] += p1 * v1.y; O[1][1][2] += p1 * v1.z; O[1][1][3] += p1 * v1.w;
        }
    }
#pragma unroll
    for (int r = 0; r < 2; r++) {
        int grow = q0 + 16 * r + ty;
        float gsc = gate[be * KSEL + grow] / l[r];
        float4 o0, o1;
        o0.x = O[r][0][0] * gsc; o0.y = O[r][0][1] * gsc; o0.z = O[r][0][2] * gsc; o0.w = O[r][0][3] * gsc;
        o1.x = O[r][1][0] * gsc; o1.y = O[r][1][1] * gsc; o1.z = O[r][1][2] * gsc; o1.w = O[r][1][3] * gsc;
        *(float4*)(AV + ((size_t)be * KSEL + grow) * HPD + tx * 4) = o0;
        *(float4*)(AV + ((size_t)be * KSEL + grow) * HPD + 64 + tx * 4) = o1;
    }
}

// ---------------- 6. out projection AV(64x128) @ Wo[e](128x128 tile) + NON-ATOMIC scatter ----------------
// Called once per expert e (8 sequential launches). Within one launch the scatter
// targets out[b, idx[b,e,*], :] whose rows are DISTINCT (top-k indices unique per
// (b,e)) -> each out element touched by exactly one thread -> plain RMW, no atomics.
__global__ __launch_bounds__(256) void proj_kernel(const float* __restrict__ AV,
                                                   const float* __restrict__ Wo,
                                                   const int* __restrict__ topk_idx,
                                                   float* __restrict__ out,
                                                   int e) {
    __shared__ float As[16][68];
    __shared__ float Bs[16][132];
    __shared__ int rows_s[64];
    int mt = blockIdx.x, nt = blockIdx.y, b = blockIdx.z;
    int be = b * EE + e;
    int tid = threadIdx.x, tx = tid & 15, ty = tid >> 4;
    if (tid < 64) rows_s[tid] = topk_idx[be * KSEL + mt * 64 + tid];
    __syncthreads();
    int n0 = nt * 128;
    float acc[4][2][4];
#pragma unroll
    for (int r = 0; r < 4; r++)
#pragma unroll
        for (int g = 0; g < 2; g++)
#pragma unroll
            for (int c = 0; c < 4; c++) acc[r][g][c] = 0.f;
    const float* ab = AV + ((size_t)be * KSEL + mt * 64) * HPD;
    const float* wb = Wo + (size_t)e * HPD * HH;
    int am = tid >> 2, akg = tid & 3;
    int bkk = tid >> 4, bng = tid & 15;
    for (int k0 = 0; k0 < HPD; k0 += 16) {
        float4 a4 = *(const float4*)(ab + (size_t)am * HPD + k0 + akg * 4);
        float4 b0 = *(const float4*)(wb + (size_t)(k0 + bkk) * HH + n0 + bng * 4);
        float4 b1 = *(const float4*)(wb + (size_t)(k0 + bkk) * HH + n0 + 64 + bng * 4);
        As[akg * 4 + 0][am] = a4.x; As[akg * 4 + 1][am] = a4.y;
        As[akg * 4 + 2][am] = a4.z; As[akg * 4 + 3][am] = a4.w;
        *(float4*)&Bs[bkk][bng * 4] = b0;
        *(float4*)&Bs[bkk][64 + bng * 4] = b1;
        __syncthreads();
#pragma unroll
        for (int kk = 0; kk < 16; kk++) {
            float ar[4];
#pragma unroll
            for (int r = 0; r < 4; r++) ar[r] = As[kk][16 * r + ty];
            float4 v0 = *(float4*)&Bs[kk][tx * 4];
            float4 v1 = *(float4*)&Bs[kk][64 + tx * 4];
#pragma unroll
            for (int r = 0; r < 4; r++) {
                acc[r][0][0] += ar[r] * v0.x; acc[r][0][1] += ar[r] * v0.y;
                acc[r][0][2] += ar[r] * v0.z; acc[r][0][3] += ar[r] * v0.w;
                acc[r][1][0] += ar[r] * v1.x; acc[r][1][1] += ar[r] * v1.y;
                acc[r][1][2] += ar[r] * v1.z; acc[r][1][3] += ar[r] * v1.w;
            }
        }
        __syncthreads();
    }
#pragma unroll
    for (int r = 0; r < 4; r++) {
        int pos = rows_s[16 * r + ty];
        float* ob = out + ((size_t)b * TT + pos) * HH + n0;
#pragma unroll
        for (int g = 0; g < 2; g++) {
            float4* p = (float4*)(ob + g * 64 + tx * 4);
            float4 cur = *p;
            cur.x += acc[r][g][0]; cur.y += acc[r][g][1];
            cur.z += acc[r][g][2]; cur.w += acc[r][g][3];
            *p = cur;
        }
    }
}

extern "C" void kernel_launch(void* const* d_in, const int* in_sizes, int n_in,
                              void* d_out, int out_size, void* d_ws, size_t ws_size,
                              hipStream_t stream) {
    const float* X    = (const float*)d_in[0];
    const float* Wr   = (const float*)d_in[1];
    const float* Wqkv = (const float*)d_in[2];
    const float* Wo   = (const float*)d_in[3];
    float* out = (float*)d_out;
    char* ws = (char*)d_ws;
    float* L    = (float*)(ws + OFF_L);
    int*   idx  = (int*)(ws + OFF_IDX);
    float* gate = (float*)(ws + OFF_GATE);
    float* QKV  = (float*)(ws + OFF_QKV);
    float* AV   = (float*)(ws + OFF_AV);

    hipMemsetAsync(d_out, 0, (size_t)BB * TT * HH * sizeof(float), stream);
    router_kernel<<<BB * TT / 4, 256, 0, stream>>>(X, Wr, L);
    topk_kernel<<<BB * EE, 1024, 0, stream>>>(L, idx, gate);
    qkv_kernel<<<dim3(KSEL / 64, 3, BB * EE), 256, 0, stream>>>(X, Wqkv, idx, QKV);
    rope_kernel<<<BB * EE * KSEL / 4, 256, 0, stream>>>(QKV, idx);
    attn_kernel<<<dim3(KSEL / 32, BB * EE), 256, 0, stream>>>(QKV, idx, gate, AV);
    for (int e = 0; e < EE; e++)
        proj_kernel<<<dim3(KSEL / 64, HH / 128, BB), 256, 0, stream>>>(AV, Wo, idx, out, e);
}

// Round 3
// 911.746 us; speedup vs baseline: 1.6905x; 1.3264x over previous
//
#include <hip/hip_runtime.h>
#include <math.h>

#define BB 4
#define TT 8192
#define EE 8
#define HH 1024
#define HPD 128
#define KSEL 1024
#define QW 384   // 3*HP

typedef __attribute__((ext_vector_type(8))) short s16x8;
typedef __attribute__((ext_vector_type(4))) float f32x4;

// ---- workspace layout (bytes) ----
#define OFF_L    ((size_t)0)                                   // float[B*T*E]          1 MB
#define OFF_IDX  (OFF_L    + (size_t)BB*TT*EE*4)               // int[B*E*K]            128 KB
#define OFF_GATE (OFF_IDX  + (size_t)BB*EE*KSEL*4)             // float[B*E*K]          128 KB
#define OFF_TRIG (OFF_GATE + (size_t)BB*EE*KSEL*4)             // float2[8192*32]       2 MB
#define OFF_QH   (OFF_TRIG + (size_t)TT*32*8)                  // bf16[B*E*K*128]       8 MB
#define OFF_QL   (OFF_QH   + (size_t)BB*EE*KSEL*HPD*2)
#define OFF_KH   (OFF_QL   + (size_t)BB*EE*KSEL*HPD*2)
#define OFF_KL   (OFF_KH   + (size_t)BB*EE*KSEL*HPD*2)
#define OFF_VT   (OFF_KL   + (size_t)BB*EE*KSEL*HPD*2)         // bf16[B*E*128*K] transposed
#define OFF_AV   (OFF_VT   + (size_t)BB*EE*KSEL*HPD*2)         // float[B*E*K*128]      16 MB

static __device__ inline unsigned short f2bf(float x) {        // fp32 -> bf16 bits, RNE
    unsigned u = __float_as_uint(x);
    return (unsigned short)((u + 0x7fffu + ((u >> 16) & 1u)) >> 16);
}
static __device__ inline f32x4 mfma16(s16x8 a, s16x8 b, f32x4 c) {
    return __builtin_amdgcn_mfma_f32_16x16x32_bf16(a, b, c, 0, 0, 0);
}

// ---------------- 0. trig table: cos/sin(pos * 10000^(-2j/64)) in fp64 ----------------
__global__ __launch_bounds__(256) void trig_kernel(float2* __restrict__ trig) {
    int i = blockIdx.x * 256 + threadIdx.x;      // i < 8192*32
    int pos = i >> 5, j = i & 31;
    double inv = pow(10000.0, -(double)(2 * j) / 64.0);
    double a = (double)pos * inv;
    trig[i] = make_float2((float)cos(a), (float)sin(a));
}

// ---------------- 1. router: L[b,t,e] = X[b,t,:] . Wr[e,:]  (fp64 accum) ----------------
__global__ __launch_bounds__(256) void router_kernel(const float* __restrict__ X,
                                                     const float* __restrict__ Wr,
                                                     float* __restrict__ L) {
    __shared__ float wr_s[EE * HH];
    int tid = threadIdx.x;
    for (int i = tid; i < EE * HH; i += 256) wr_s[i] = Wr[i];
    __syncthreads();
    int wave = tid >> 6, lane = tid & 63;
    int row = blockIdx.x * 4 + wave;              // row in [0, B*T)
    const float* xr = X + (size_t)row * HH;
    double acc[EE];
#pragma unroll
    for (int e = 0; e < EE; e++) acc[e] = 0.0;
#pragma unroll
    for (int it = 0; it < 4; it++) {
        int d0 = it * 256 + lane * 4;
        float4 x4 = *(const float4*)(xr + d0);
#pragma unroll
        for (int e = 0; e < EE; e++) {
            float4 w4 = *(const float4*)(wr_s + e * HH + d0);
            acc[e] += (double)x4.x * w4.x + (double)x4.y * w4.y +
                      (double)x4.z * w4.z + (double)x4.w * w4.w;
        }
    }
#pragma unroll
    for (int off = 32; off > 0; off >>= 1)
#pragma unroll
        for (int e = 0; e < EE; e++) acc[e] += __shfl_xor(acc[e], off, 64);
    if (lane < EE) L[(size_t)row * EE + lane] = (float)acc[lane];
}

// ---------------- 2. top-k (bitonic) then re-sort selected by index ASC ----------------
// Output indices ascending => mask pos_q>=pos_k becomes causal-by-rank (positions
// distinct), enabling tile skipping in attention. Output set identical to lax.top_k.
__global__ __launch_bounds__(1024) void topk_kernel(const float* __restrict__ L,
                                                    int* __restrict__ topk_idx,
                                                    float* __restrict__ gate) {
    __shared__ unsigned long long s[TT];          // 64 KB
    int be = blockIdx.x, b = be >> 3, e = be & 7;
    int tid = threadIdx.x;
    for (int t = tid; t < TT; t += 1024) {
        float v = L[((size_t)b * TT + t) * EE + e];
        unsigned u = __float_as_uint(v);
        u ^= (u >> 31) ? 0xFFFFFFFFu : 0x80000000u;   // sortable: asc uint == asc float
        unsigned inv = ~u;                            // asc inv == desc float
        s[t] = ((unsigned long long)inv << 32) | (unsigned)t;
    }
    __syncthreads();
    for (int size = 2; size <= TT; size <<= 1) {
        for (int stride = size >> 1; stride > 0; stride >>= 1) {
            for (int t = tid; t < TT / 2; t += 1024) {
                int j = t & (stride - 1);
                int lo = ((t ^ j) << 1) | j;
                int hi = lo + stride;
                unsigned long long a = s[lo], c = s[hi];
                bool asc = ((lo & size) == 0);
                if ((a > c) == asc) { s[lo] = c; s[hi] = a; }
            }
            __syncthreads();
        }
    }
    // rebuild keys for top KSEL: (idx<<32)|gate_bits, sort ascending by idx
    unsigned long long key = 0;
    if (tid < KSEL) {
        int idx = (int)(unsigned)s[tid];
        float v = L[((size_t)b * TT + idx) * EE + e];
        float g = 1.0f / (1.0f + expf(-v));
        key = ((unsigned long long)(unsigned)idx << 32) | __float_as_uint(g);
    }
    __syncthreads();
    if (tid < KSEL) s[tid] = key;
    __syncthreads();
    for (int size = 2; size <= KSEL; size <<= 1) {
        for (int stride = size >> 1; stride > 0; stride >>= 1) {
            int t = tid;
            if (t < KSEL / 2) {
                int j = t & (stride - 1);
                int lo = ((t ^ j) << 1) | j;
                int hi = lo + stride;
                unsigned long long a = s[lo], c = s[hi];
                bool asc = ((lo & size) == 0);
                if ((a > c) == asc) { s[lo] = c; s[hi] = a; }
            }
            __syncthreads();
        }
    }
    if (tid < KSEL) {
        topk_idx[be * KSEL + tid] = (int)(s[tid] >> 32);
        gate[be * KSEL + tid] = __uint_as_float((unsigned)s[tid]);
    }
}

// ---------------- 3. QKV GEMM + fused RoPE + bf16 hi/lo split + V transpose ----------------
// nt=0 -> Q (rope dims 0..63, scale 1/sqrt(HP), split to Qh/Ql)
// nt=1 -> K (rope dims 0..63, split to Kh/Kl)
// nt=2 -> V (plain bf16, transposed to Vt[be][d=128][k=1024])
__global__ __launch_bounds__(256) void qkv_kernel(const float* __restrict__ X,
                                                  const float* __restrict__ Wqkv,
                                                  const int* __restrict__ topk_idx,
                                                  const float2* __restrict__ trig,
                                                  unsigned short* __restrict__ Qh,
                                                  unsigned short* __restrict__ Ql,
                                                  unsigned short* __restrict__ Kh,
                                                  unsigned short* __restrict__ Kl,
                                                  unsigned short* __restrict__ Vt) {
    __shared__ float As[16][68];    // [kk][m]
    __shared__ float Bs[16][132];   // [kk][n]
    __shared__ int rows_s[64];
    __shared__ unsigned short T[128][72];   // V transpose staging
    int mt = blockIdx.x, nt = blockIdx.y, be = blockIdx.z;
    int b = be >> 3, e = be & 7;
    int tid = threadIdx.x, tx = tid & 15, ty = tid >> 4;
    if (tid < 64) rows_s[tid] = topk_idx[be * KSEL + mt * 64 + tid];
    __syncthreads();
    int n0 = nt * 128;
    float acc[4][2][4];
#pragma unroll
    for (int r = 0; r < 4; r++)
#pragma unroll
        for (int g = 0; g < 2; g++)
#pragma unroll
            for (int c = 0; c < 4; c++) acc[r][g][c] = 0.f;
    const float* xb = X + (size_t)b * TT * HH;
    const float* wb = Wqkv + (size_t)e * HH * QW;
    int am = tid >> 2, akg = tid & 3;
    size_t arow = (size_t)rows_s[am] * HH;
    int bkk = tid >> 4, bng = tid & 15;
    for (int k0 = 0; k0 < HH; k0 += 16) {
        float4 a4 = *(const float4*)(xb + arow + k0 + akg * 4);
        float4 b0 = *(const float4*)(wb + (size_t)(k0 + bkk) * QW + n0 + bng * 4);
        float4 b1 = *(const float4*)(wb + (size_t)(k0 + bkk) * QW + n0 + 64 + bng * 4);
        As[akg * 4 + 0][am] = a4.x; As[akg * 4 + 1][am] = a4.y;
        As[akg * 4 + 2][am] = a4.z; As[akg * 4 + 3][am] = a4.w;
        *(float4*)&Bs[bkk][bng * 4] = b0;
        *(float4*)&Bs[bkk][64 + bng * 4] = b1;
        __syncthreads();
#pragma unroll
        for (int kk = 0; kk < 16; kk++) {
            float ar[4];
#pragma unroll
            for (int r = 0; r < 4; r++) ar[r] = As[kk][16 * r + ty];
            float4 v0 = *(float4*)&Bs[kk][tx * 4];
            float4 v1 = *(float4*)&Bs[kk][64 + tx * 4];
#pragma unroll
            for (int r = 0; r < 4; r++) {
                acc[r][0][0] += ar[r] * v0.x; acc[r][0][1] += ar[r] * v0.y;
                acc[r][0][2] += ar[r] * v0.z; acc[r][0][3] += ar[r] * v0.w;
                acc[r][1][0] += ar[r] * v1.x; acc[r][1][1] += ar[r] * v1.y;
                acc[r][1][2] += ar[r] * v1.z; acc[r][1][3] += ar[r] * v1.w;
            }
        }
        __syncthreads();
    }
    if (nt < 2) {
        // RoPE on local dims 0..63 (g==0). pair (j, j+32), partner = lane xor 8.
#pragma unroll
        for (int r = 0; r < 4; r++) {
            int pos = rows_s[16 * r + ty];
#pragma unroll
            for (int c = 0; c < 4; c++) {
                float own = acc[r][0][c];
                float oth = __shfl_xor(own, 8, 64);
                float2 sc = trig[pos * 32 + ((tx & 7) * 4 + c)];
                acc[r][0][c] = (tx < 8) ? own * sc.x - oth * sc.y
                                        : own * sc.x + oth * sc.y;
            }
        }
        float qs = (nt == 0) ? 0.08838834764831845f : 1.0f;   // 1/sqrt(128) folded into Q
        unsigned short* Ph = (nt == 0) ? Qh : Kh;
        unsigned short* Pl = (nt == 0) ? Ql : Kl;
#pragma unroll
        for (int r = 0; r < 4; r++)
#pragma unroll
            for (int g = 0; g < 2; g++) {
                ushort4 hv, lv;
                float x0 = acc[r][g][0] * qs, x1 = acc[r][g][1] * qs;
                float x2 = acc[r][g][2] * qs, x3 = acc[r][g][3] * qs;
                hv.x = f2bf(x0); hv.y = f2bf(x1); hv.z = f2bf(x2); hv.w = f2bf(x3);
                lv.x = f2bf(x0 - __uint_as_float((unsigned)hv.x << 16));
                lv.y = f2bf(x1 - __uint_as_float((unsigned)hv.y << 16));
                lv.z = f2bf(x2 - __uint_as_float((unsigned)hv.z << 16));
                lv.w = f2bf(x3 - __uint_as_float((unsigned)hv.w << 16));
                size_t off = ((size_t)be * KSEL + mt * 64 + 16 * r + ty) * HPD + g * 64 + tx * 4;
                *(ushort4*)(Ph + off) = hv;
                *(ushort4*)(Pl + off) = lv;
            }
    } else {
        // V: transpose 64x128 tile through LDS, write Vt[be][d][k] coalesced
#pragma unroll
        for (int r = 0; r < 4; r++)
#pragma unroll
            for (int g = 0; g < 2; g++)
#pragma unroll
                for (int c = 0; c < 4; c++)
                    T[g * 64 + tx * 4 + c][16 * r + ty] = f2bf(acc[r][g][c]);
        __syncthreads();
        for (int j = tid; j < 1024; j += 256) {
            int row = j >> 3, seg = j & 7;
            uint4 v = *(uint4*)&T[row][seg * 8];
            *(uint4*)(Vt + ((size_t)be * HPD + row) * KSEL + mt * 64 + seg * 8) = v;
        }
    }
}

// ---------------- 4. causal flash attention, MFMA 16x16x32 bf16 ----------------
// Sorted indices => standard causal mask by rank; process k-tiles 0..qt only.
// QK^T: 3-pass hi/lo split (fp32-grade scores). PV: plain bf16 P,V.
__global__ __launch_bounds__(256) void attn_kernel(const unsigned short* __restrict__ Qh,
                                                   const unsigned short* __restrict__ Ql,
                                                   const unsigned short* __restrict__ Kh,
                                                   const unsigned short* __restrict__ Kl,
                                                   const unsigned short* __restrict__ Vt,
                                                   const float* __restrict__ gate,
                                                   float* __restrict__ AV) {
    __shared__ __align__(16) unsigned short sm[31232];  // 62464 B
    unsigned short* sKH = sm;                 // [64][136]
    unsigned short* sKL = sm + 8704;          // [64][136]
    unsigned short* sVT = sm + 17408;         // [128][72]
    unsigned short* sP  = sm + 26624;         // [4 waves][16][72]
    int tid = threadIdx.x;
    int wy = tid >> 6, lane = tid & 63, ln = lane & 15, quad = lane >> 4;
    int qtx = blockIdx.x, be = blockIdx.y;
    int qt = (be & 16) ? (15 - qtx) : qtx;    // complementary pairing for load balance
    int q0w = qt * 64 + wy * 16;
    // Q fragments (A-layout: m=ln, k=quad*8+j), resident in regs
    s16x8 qh[4], qlo[4];
    {
        const unsigned short* qrh = Qh + ((size_t)be * KSEL + q0w + ln) * HPD + quad * 8;
        const unsigned short* qrl = Ql + ((size_t)be * KSEL + q0w + ln) * HPD + quad * 8;
#pragma unroll
        for (int dc = 0; dc < 4; dc++) {
            qh[dc]  = *(const s16x8*)(qrh + dc * 32);
            qlo[dc] = *(const s16x8*)(qrl + dc * 32);
        }
    }
    f32x4 O[8];
#pragma unroll
    for (int f = 0; f < 8; f++) O[f] = (f32x4){0.f, 0.f, 0.f, 0.f};
    float m_[4] = {-INFINITY, -INFINITY, -INFINITY, -INFINITY};
    float l_[4] = {0.f, 0.f, 0.f, 0.f};
    const unsigned short* gKH = Kh + (size_t)be * KSEL * HPD;
    const unsigned short* gKL = Kl + (size_t)be * KSEL * HPD;
    const unsigned short* gVT = Vt + (size_t)be * HPD * KSEL;
    unsigned short* Pw = sP + wy * 1152;
    for (int kt = 0; kt <= qt; kt++) {
        __syncthreads();
        for (int j = tid; j < 1024; j += 256) {          // K tiles (hi+lo)
            int row = j >> 4, seg = j & 15;
            size_t g = (size_t)(kt * 64 + row) * HPD + seg * 8;
            *(uint4*)(sKH + row * 136 + seg * 8) = *(const uint4*)(gKH + g);
            *(uint4*)(sKL + row * 136 + seg * 8) = *(const uint4*)(gKL + g);
        }
        for (int j = tid; j < 1024; j += 256) {          // Vt tile
            int row = j >> 3, seg = j & 7;
            *(uint4*)(sVT + row * 72 + seg * 8) =
                *(const uint4*)(gVT + (size_t)row * KSEL + kt * 64 + seg * 8);
        }
        __syncthreads();
        // S = Q K^T  (3-pass split)
        f32x4 s4[4];
#pragma unroll
        for (int f = 0; f < 4; f++) s4[f] = (f32x4){0.f, 0.f, 0.f, 0.f};
#pragma unroll
        for (int dc = 0; dc < 4; dc++) {
#pragma unroll
            for (int f = 0; f < 4; f++) {
                s16x8 kh = *(const s16x8*)(sKH + (f * 16 + ln) * 136 + dc * 32 + quad * 8);
                s16x8 kl = *(const s16x8*)(sKL + (f * 16 + ln) * 136 + dc * 32 + quad * 8);
                s4[f] = mfma16(qh[dc], kh, s4[f]);
                s4[f] = mfma16(qlo[dc], kh, s4[f]);
                s4[f] = mfma16(qh[dc], kl, s4[f]);
            }
        }
        if (kt == qt) {                                   // causal mask on diagonal tile
            int qloc = wy * 16 + quad * 4;
#pragma unroll
            for (int f = 0; f < 4; f++)
#pragma unroll
                for (int r = 0; r < 4; r++)
                    if (f * 16 + ln > qloc + r) s4[f][r] = -INFINITY;
        }
        float alpha[4];
#pragma unroll
        for (int r = 0; r < 4; r++) {
            float mr = fmaxf(fmaxf(s4[0][r], s4[1][r]), fmaxf(s4[2][r], s4[3][r]));
            mr = fmaxf(mr, __shfl_xor(mr, 1, 64));
            mr = fmaxf(mr, __shfl_xor(mr, 2, 64));
            mr = fmaxf(mr, __shfl_xor(mr, 4, 64));
            mr = fmaxf(mr, __shfl_xor(mr, 8, 64));
            float mn = fmaxf(m_[r], mr);
            alpha[r] = __expf(m_[r] - mn);
            float rs = 0.f;
#pragma unroll
            for (int f = 0; f < 4; f++) {
                float p = __expf(s4[f][r] - mn);
                s4[f][r] = p; rs += p;
            }
            rs += __shfl_xor(rs, 1, 64);
            rs += __shfl_xor(rs, 2, 64);
            rs += __shfl_xor(rs, 4, 64);
            rs += __shfl_xor(rs, 8, 64);
            l_[r] = l_[r] * alpha[r] + rs;
            m_[r] = mn;
        }
        // P -> LDS (C-layout out, A-layout back in); per-wave region, no barrier
#pragma unroll
        for (int f = 0; f < 4; f++)
#pragma unroll
            for (int r = 0; r < 4; r++)
                Pw[(quad * 4 + r) * 72 + f * 16 + ln] = f2bf(s4[f][r]);
#pragma unroll
        for (int f = 0; f < 8; f++) {
            O[f][0] *= alpha[0]; O[f][1] *= alpha[1];
            O[f][2] *= alpha[2]; O[f][3] *= alpha[3];
        }
        s16x8 p0 = *(const s16x8*)(Pw + ln * 72 + quad * 8);
        s16x8 p1 = *(const s16x8*)(Pw + ln * 72 + 32 + quad * 8);
#pragma unroll
        for (int f = 0; f < 8; f++) {
            s16x8 v0 = *(const s16x8*)(sVT + (f * 16 + ln) * 72 + quad * 8);
            s16x8 v1 = *(const s16x8*)(sVT + (f * 16 + ln) * 72 + 32 + quad * 8);
            O[f] = mfma16(p0, v0, O[f]);
            O[f] = mfma16(p1, v1, O[f]);
        }
    }
#pragma unroll
    for (int r = 0; r < 4; r++) {
        int row = q0w + quad * 4 + r;
        float gs = gate[be * KSEL + row] / l_[r];
        float* dst = AV + ((size_t)be * KSEL + row) * HPD + ln;
#pragma unroll
        for (int f = 0; f < 8; f++) dst[f * 16] = O[f][r] * gs;
    }
}

// ---------------- 5. out projection AV(64x128) @ Wo[e](128x128 tile) + NON-ATOMIC scatter ----------------
__global__ __launch_bounds__(256) void proj_kernel(const float* __restrict__ AV,
                                                   const float* __restrict__ Wo,
                                                   const int* __restrict__ topk_idx,
                                                   float* __restrict__ out,
                                                   int e) {
    __shared__ float As[16][68];
    __shared__ float Bs[16][132];
    __shared__ int rows_s[64];
    int mt = blockIdx.x, nt = blockIdx.y, b = blockIdx.z;
    int be = b * EE + e;
    int tid = threadIdx.x, tx = tid & 15, ty = tid >> 4;
    if (tid < 64) rows_s[tid] = topk_idx[be * KSEL + mt * 64 + tid];
    __syncthreads();
    int n0 = nt * 128;
    float acc[4][2][4];
#pragma unroll
    for (int r = 0; r < 4; r++)
#pragma unroll
        for (int g = 0; g < 2; g++)
#pragma unroll
            for (int c = 0; c < 4; c++) acc[r][g][c] = 0.f;
    const float* ab = AV + ((size_t)be * KSEL + mt * 64) * HPD;
    const float* wb = Wo + (size_t)e * HPD * HH;
    int am = tid >> 2, akg = tid & 3;
    int bkk = tid >> 4, bng = tid & 15;
    for (int k0 = 0; k0 < HPD; k0 += 16) {
        float4 a4 = *(const float4*)(ab + (size_t)am * HPD + k0 + akg * 4);
        float4 b0 = *(const float4*)(wb + (size_t)(k0 + bkk) * HH + n0 + bng * 4);
        float4 b1 = *(const float4*)(wb + (size_t)(k0 + bkk) * HH + n0 + 64 + bng * 4);
        As[akg * 4 + 0][am] = a4.x; As[akg * 4 + 1][am] = a4.y;
        As[akg * 4 + 2][am] = a4.z; As[akg * 4 + 3][am] = a4.w;
        *(float4*)&Bs[bkk][bng * 4] = b0;
        *(float4*)&Bs[bkk][64 + bng * 4] = b1;
        __syncthreads();
#pragma unroll
        for (int kk = 0; kk < 16; kk++) {
            float ar[4];
#pragma unroll
            for (int r = 0; r < 4; r++) ar[r] = As[kk][16 * r + ty];
            float4 v0 = *(float4*)&Bs[kk][tx * 4];
            float4 v1 = *(float4*)&Bs[kk][64 + tx * 4];
#pragma unroll
            for (int r = 0; r < 4; r++) {
                acc[r][0][0] += ar[r] * v0.x; acc[r][0][1] += ar[r] * v0.y;
                acc[r][0][2] += ar[r] * v0.z; acc[r][0][3] += ar[r] * v0.w;
                acc[r][1][0] += ar[r] * v1.x; acc[r][1][1] += ar[r] * v1.y;
                acc[r][1][2] += ar[r] * v1.z; acc[r][1][3] += ar[r] * v1.w;
            }
        }
        __syncthreads();
    }
#pragma unroll
    for (int r = 0; r < 4; r++) {
        int pos = rows_s[16 * r + ty];
        float* ob = out + ((size_t)b * TT + pos) * HH + n0;
#pragma unroll
        for (int g = 0; g < 2; g++) {
            float4* p = (float4*)(ob + g * 64 + tx * 4);
            float4 cur = *p;
            cur.x += acc[r][g][0]; cur.y += acc[r][g][1];
            cur.z += acc[r][g][2]; cur.w += acc[r][g][3];
            *p = cur;
        }
    }
}

extern "C" void kernel_launch(void* const* d_in, const int* in_sizes, int n_in,
                              void* d_out, int out_size, void* d_ws, size_t ws_size,
                              hipStream_t stream) {
    const float* X    = (const float*)d_in[0];
    const float* Wr   = (const float*)d_in[1];
    const float* Wqkv = (const float*)d_in[2];
    const float* Wo   = (const float*)d_in[3];
    float* out = (float*)d_out;
    char* ws = (char*)d_ws;
    float* L    = (float*)(ws + OFF_L);
    int*   idx  = (int*)(ws + OFF_IDX);
    float* gate = (float*)(ws + OFF_GATE);
    float2* trig = (float2*)(ws + OFF_TRIG);
    unsigned short* Qh = (unsigned short*)(ws + OFF_QH);
    unsigned short* Ql = (unsigned short*)(ws + OFF_QL);
    unsigned short* Kh = (unsigned short*)(ws + OFF_KH);
    unsigned short* Kl = (unsigned short*)(ws + OFF_KL);
    unsigned short* Vt = (unsigned short*)(ws + OFF_VT);
    float* AV   = (float*)(ws + OFF_AV);

    hipMemsetAsync(d_out, 0, (size_t)BB * TT * HH * sizeof(float), stream);
    trig_kernel<<<TT * 32 / 256, 256, 0, stream>>>(trig);
    router_kernel<<<BB * TT / 4, 256, 0, stream>>>(X, Wr, L);
    topk_kernel<<<BB * EE, 1024, 0, stream>>>(L, idx, gate);
    qkv_kernel<<<dim3(KSEL / 64, 3, BB * EE), 256, 0, stream>>>(X, Wqkv, idx, trig,
                                                                Qh, Ql, Kh, Kl, Vt);
    attn_kernel<<<dim3(16, BB * EE), 256, 0, stream>>>(Qh, Ql, Kh, Kl, Vt, gate, AV);
    for (int e = 0; e < EE; e++)
        proj_kernel<<<dim3(KSEL / 64, HH / 128, BB), 256, 0, stream>>>(AV, Wo, idx, out, e);
}